// Round 3
// baseline (49135.019 us; speedup 1.0000x reference)
//
#include <hip/hip_runtime.h>
#include <hip/hip_bf16.h>
#include <hip/hip_cooperative_groups.h>

namespace cg = cooperative_groups;

#define T_STEPS 512
#define BATCH   64
#define HID     1024
#define NLAYER  3
#define EPSV    1e-5f

typedef __attribute__((ext_vector_type(8))) short    short8;
typedef __attribute__((ext_vector_type(8))) _Float16 f16x8;
typedef __attribute__((ext_vector_type(4))) float    f32x4;

// packed activation layout within one [64 rows x 1024 k] fp16 buffer (65536 elems):
// [kc(8)][mt(4)][ki(4)][lane(64)][j(8)]  where row = mt*16 + (lane&15),
// k = kc*128 + ki*32 + (lane>>4)*8 + j
__device__ __forceinline__ int act_pack_idx(int row, int k) {
  int mt = row >> 4, lr = row & 15;
  int kc = k >> 7;
  int ki = (k >> 5) & 3;
  int lh = (k >> 3) & 3;
  int j  = k & 7;
  int lane = lr | (lh << 4);
  return ((((kc * 4 + mt) * 4 + ki) * 64) + lane) * 8 + j;
}

__device__ __forceinline__ float sigmoidf_(float v) {
  return 1.f / (1.f + __expf(-v));
}

// sum-reduce two values across 512 threads (8 waves)
__device__ __forceinline__ void reduce2_512(float& a, float& b, float* red) {
  #pragma unroll
  for (int o = 32; o; o >>= 1) {
    a += __shfl_xor(a, o, 64);
    b += __shfl_xor(b, o, 64);
  }
  int wv = threadIdx.x >> 6;
  if ((threadIdx.x & 63) == 0) { red[wv * 2] = a; red[wv * 2 + 1] = b; }
  __syncthreads();
  a = red[0]; b = red[1];
  #pragma unroll
  for (int i = 1; i < 8; ++i) { a += red[i * 2]; b += red[i * 2 + 1]; }
  __syncthreads();
}

// Wpack per layer: [ncb(64)][kc(16)][nt(4)][ki(4)][lane(64)][j(8)]
// n = ncb*64 + nt*16 + (lane&15); k = kc*128 + ki*32 + (lane>>4)*8 + j
// k<1024 -> Wx[n][k], else Wh[n][k-1024]
__global__ __launch_bounds__(256) void pack_weights(
    const float* __restrict__ Wx, const float* __restrict__ Wh,
    _Float16* __restrict__ Wpack) {
  long idx = (long)blockIdx.x * 256 + threadIdx.x;  // exactly 3*4096*2048 threads
  int l  = (int)(idx / 8388608);
  int r  = (int)(idx % 8388608);
  int ncb = r >> 17;
  int r2 = r & 131071;
  int kc = r2 >> 13;
  int r3 = r2 & 8191;
  int nt = r3 >> 11;
  int r4 = r3 & 2047;
  int ki = r4 >> 9;
  int r5 = r4 & 511;
  int lane = r5 >> 3, j = r5 & 7;
  int n = ncb * 64 + nt * 16 + (lane & 15);
  int k = kc * 128 + ki * 32 + ((lane >> 4) << 3) + j;
  float v = (k < 1024) ? Wx[((size_t)l * 4096 + n) * 1024 + k]
                       : Wh[((size_t)l * 4096 + n) * 1024 + (k - 1024)];
  Wpack[idx] = (_Float16)v;
}

// zero actsA[1..2] + actsB[0..2] (5*65536 halfwords contiguous after actsA[0]),
// zero c_state, pack x[t=0] into actsA[0].
__global__ __launch_bounds__(256) void init_all(
    const float* __restrict__ x, _Float16* __restrict__ actsA,
    float* __restrict__ c_state) {
  int i = blockIdx.x * 256 + threadIdx.x;  // exactly 589824 threads
  if (i < 327680) {
    ((unsigned short*)(actsA + 65536))[i] = 0;
  } else if (i < 327680 + 196608) {
    c_state[i - 327680] = 0.f;
  } else {
    int q = i - (327680 + 196608);
    int b = q >> 10, e = q & 1023;
    actsA[act_pack_idx(b, e)] = (_Float16)x[(size_t)b * 1024 + e];
  }
}

// Persistent-weight cooperative kernel.
// Grid: 256 blocks x 512 threads. Block (ng = bid>>3, kg = bid&7) holds
// W fragments for cols [ng*128,+128), k in [kg*256,+256), all 3 layers:
// 24 f16x8 regs/lane (96 VGPR). kg<4 -> input half (actsA), kg>=4 -> recurrent
// half (actsB). Same-kg blocks are bid≡kg (mod 8) -> same XCD -> A-slice L2-local.
__global__ __launch_bounds__(512, 2) void lstm_main(
    const float* __restrict__ x, const float* __restrict__ bh,
    const float* __restrict__ ln_g, const float* __restrict__ ln_b,
    const float* __restrict__ lnc_g, const float* __restrict__ lnc_b,
    const _Float16* __restrict__ Wpack,
    _Float16* __restrict__ actsA, _Float16* __restrict__ actsB,
    float* __restrict__ pc, float* __restrict__ c_state,
    float* __restrict__ out_all) {
  cg::grid_group grid = cg::this_grid();
  __shared__ _Float16 ldsA[16384];   // one 64x256 A-slice (32 KB)
  __shared__ float red[16];
  const int bid = blockIdx.x, tid = threadIdx.x;
  const int ng = bid >> 3, kg = bid & 7;
  const int wv = tid >> 6, lane = tid & 63;

  // ---- preload weights into registers (once) ----
  f16x8 Wreg[3][2][4];
  {
    const int ncb = ng * 2 + (wv >> 2), ntp = wv & 3;
    #pragma unroll
    for (int l = 0; l < 3; ++l)
      #pragma unroll
      for (int kcL = 0; kcL < 2; ++kcL)
        #pragma unroll
        for (int ki = 0; ki < 4; ++ki) {
          size_t base = ((((size_t)(l * 64 + ncb) * 16 + (kg * 2 + kcL)) * 4 + ntp) * 4 + ki);
          Wreg[l][kcL][ki] = *(const f16x8*)(Wpack + base * 512 + lane * 8);
        }
  }

  for (int s = 0; s < T_STEPS + NLAYER - 1; ++s) {
    // ---------------- phase A: partial GEMM with register weights ----------------
    #pragma unroll
    for (int l = 0; l < 3; ++l) {
      const int t = s - l;
      if (t >= 0 && t < T_STEPS) {
        const _Float16* src = (kg < 4) ? (actsA + l * 65536 + kg * 16384)
                                       : (actsB + l * 65536 + (kg - 4) * 16384);
        __syncthreads();   // previous layer's LDS readers done
        #pragma unroll
        for (int it = 0; it < 4; ++it) {
          const int o = (it * 512 + tid) * 8;
          *(short8*)(&ldsA[o]) = *(const short8*)(src + o);
        }
        __syncthreads();
        f32x4 acc[4];
        #pragma unroll
        for (int mt = 0; mt < 4; ++mt) acc[mt] = (f32x4){0.f, 0.f, 0.f, 0.f};
        #pragma unroll
        for (int mt = 0; mt < 4; ++mt)
          #pragma unroll
          for (int kcL = 0; kcL < 2; ++kcL)
            #pragma unroll
            for (int ki = 0; ki < 4; ++ki) {
              f16x8 a = *(const f16x8*)(&ldsA[((kcL * 16 + mt * 4 + ki) * 64 + lane) * 8]);
              acc[mt] = __builtin_amdgcn_mfma_f32_16x16x32_f16(a, Wreg[l][kcL][ki], acc[mt], 0, 0, 0);
            }
        float* prow = pc + (size_t)((kg * 3 + l) * 64) * 4096
                      + (size_t)(ng * 128 + wv * 16 + (lane & 15));
        const int r0 = (lane >> 4) << 2;
        #pragma unroll
        for (int mt = 0; mt < 4; ++mt)
          #pragma unroll
          for (int r = 0; r < 4; ++r)
            prow[(size_t)(mt * 16 + r0 + r) * 4096] = acc[mt][r];
      }
    }
    grid.sync();

    // ---------------- phase B: reduce partials + LN + cell ----------------
    if (bid < 192) {
      const int l = bid >> 6, row = bid & 63;
      const int t = s - l;
      if (t >= 0 && t < T_STEPS) {
        float vv[4][2], actv[4][2];
        #pragma unroll
        for (int g = 0; g < 4; ++g) {
          float a0 = 0.f, a1 = 0.f;
          #pragma unroll
          for (int kgi = 0; kgi < 8; ++kgi) {
            const float* p = pc + (size_t)((kgi * 3 + l) * 64 + row) * 4096
                             + g * 1024 + tid * 2;
            a0 += p[0]; a1 += p[1];
          }
          a0 += bh[l * 4096 + g * 1024 + tid * 2];
          a1 += bh[l * 4096 + g * 1024 + tid * 2 + 1];
          vv[g][0] = a0; vv[g][1] = a1;
        }
        #pragma unroll
        for (int g = 0; g < 4; ++g) {
          float s1 = vv[g][0] + vv[g][1];
          float s2 = vv[g][0] * vv[g][0] + vv[g][1] * vv[g][1];
          reduce2_512(s1, s2, red);
          float mu  = s1 * (1.f / 1024.f);
          float var = fmaxf(s2 * (1.f / 1024.f) - mu * mu, 0.f);
          float inv = rsqrtf(var + EPSV);
          #pragma unroll
          for (int j = 0; j < 2; ++j) {
            int e = g * 1024 + tid * 2 + j;
            actv[g][j] = (vv[g][j] - mu) * inv * ln_g[l * 4096 + e] + ln_b[l * 4096 + e];
          }
        }
        float* crow = c_state + (size_t)(l * 64 + row) * 1024 + tid * 2;
        float cold[2] = {crow[0], crow[1]};
        float cn[2];
        float s1 = 0.f, s2 = 0.f;
        #pragma unroll
        for (int j = 0; j < 2; ++j) {
          float ii = sigmoidf_(actv[0][j]);
          float ff = sigmoidf_(actv[1][j]);
          float gg = tanhf(actv[2][j]);
          cn[j] = ff * cold[j] + ii * gg;
          s1 += cn[j]; s2 += cn[j] * cn[j];
        }
        crow[0] = cn[0]; crow[1] = cn[1];
        reduce2_512(s1, s2, red);
        float mu  = s1 * (1.f / 1024.f);
        float var = fmaxf(s2 * (1.f / 1024.f) - mu * mu, 0.f);
        float inv = rsqrtf(var + EPSV);
        float hn[2];
        #pragma unroll
        for (int j = 0; j < 2; ++j) {
          int e = tid * 2 + j;
          float cl = (cn[j] - mu) * inv * lnc_g[l * 1024 + e] + lnc_b[l * 1024 + e];
          hn[j] = sigmoidf_(actv[3][j]) * tanhf(cl);
        }
        _Float16* selfB = actsB + l * 65536;
        #pragma unroll
        for (int j = 0; j < 2; ++j)
          selfB[act_pack_idx(row, tid * 2 + j)] = (_Float16)hn[j];
        if (l < 2) {
          _Float16* nxtA = actsA + (l + 1) * 65536;
          #pragma unroll
          for (int j = 0; j < 2; ++j)
            nxtA[act_pack_idx(row, tid * 2 + j)] = (_Float16)hn[j];
        } else {
          float* op = out_all + ((size_t)t * BATCH + row) * 1024 + tid * 2;
          op[0] = hn[0]; op[1] = hn[1];
        }
        if (t == T_STEPS - 1) {
          float* hsec = out_all + (size_t)T_STEPS * BATCH * 1024
                        + (size_t)(l * BATCH + row) * 1024 + tid * 2;
          float* csec = hsec + (size_t)NLAYER * BATCH * 1024;
          hsec[0] = hn[0]; hsec[1] = hn[1];
          csec[0] = cn[0]; csec[1] = cn[1];
        }
      }
    } else {
      const int row = bid - 192;
      if (s + 1 < T_STEPS) {
        const float* xr = x + ((size_t)(s + 1) * BATCH + row) * 1024 + tid * 2;
        float v0 = xr[0], v1 = xr[1];
        actsA[act_pack_idx(row, tid * 2)]     = (_Float16)v0;
        actsA[act_pack_idx(row, tid * 2 + 1)] = (_Float16)v1;
      }
    }
    grid.sync();
  }
}

extern "C" void kernel_launch(void* const* d_in, const int* in_sizes, int n_in,
                              void* d_out, int out_size, void* d_ws, size_t ws_size,
                              hipStream_t stream) {
  const float* x     = (const float*)d_in[0];
  const float* Wx    = (const float*)d_in[1];
  const float* Wh    = (const float*)d_in[2];
  const float* bh    = (const float*)d_in[3];
  const float* ln_g  = (const float*)d_in[4];
  const float* ln_b  = (const float*)d_in[5];
  const float* lnc_g = (const float*)d_in[6];
  const float* lnc_b = (const float*)d_in[7];

  char* ws = (char*)d_ws;
  _Float16* Wpack = (_Float16*)ws;                               // 50331648 B
  _Float16* actsA = (_Float16*)(ws + 50331648);                  // 393216 B (3 x 65536)
  _Float16* actsB = (_Float16*)(ws + 50724864);                  // 393216 B
  float* pc      = (float*)(ws + 51118080);                      // 25165824 B (8kg x 3l x 64 x 4096 f32)
  float* c_state = (float*)(ws + 76283904);                      // 786432 B
  float* out_all = (float*)d_out;

  pack_weights<<<98304, 256, 0, stream>>>(Wx, Wh, Wpack);
  init_all<<<2304, 256, 0, stream>>>(x, actsA, c_state);

  void* args[] = { (void*)&x, (void*)&bh, (void*)&ln_g, (void*)&ln_b,
                   (void*)&lnc_g, (void*)&lnc_b, (void*)&Wpack, (void*)&actsA,
                   (void*)&actsB, (void*)&pc, (void*)&c_state, (void*)&out_all };
  hipLaunchCooperativeKernel((void*)lstm_main, dim3(256), dim3(512), args, 0, stream);
}

// Round 4
// 48758.304 us; speedup vs baseline: 1.0077x; 1.0077x over previous
//
#include <hip/hip_runtime.h>
#include <hip/hip_bf16.h>
#include <hip/hip_cooperative_groups.h>

namespace cg = cooperative_groups;

#define T_STEPS 512
#define BATCH   64
#define HID     1024
#define NLAYER  3
#define EPSV    1e-5f

typedef __attribute__((ext_vector_type(8))) short    short8;
typedef __attribute__((ext_vector_type(8))) _Float16 f16x8;
typedef __attribute__((ext_vector_type(4))) float    f32x4;

// packed activation layout within one [64 rows x 1024 k] fp16 buffer (65536 elems):
// [kc(8)][mt(4)][ki(4)][lane(64)][j(8)]  where row = mt*16 + (lane&15),
// k = kc*128 + ki*32 + (lane>>4)*8 + j
__device__ __forceinline__ int act_pack_idx(int row, int k) {
  int mt = row >> 4, lr = row & 15;
  int kc = k >> 7;
  int ki = (k >> 5) & 3;
  int lh = (k >> 3) & 3;
  int j  = k & 7;
  int lane = lr | (lh << 4);
  return ((((kc * 4 + mt) * 4 + ki) * 64) + lane) * 8 + j;
}

__device__ __forceinline__ float sigmoidf_(float v) {
  return 1.f / (1.f + __expf(-v));
}

// sum-reduce two values across 512 threads (8 waves)
__device__ __forceinline__ void reduce2_512(float& a, float& b, float* red) {
  #pragma unroll
  for (int o = 32; o; o >>= 1) {
    a += __shfl_xor(a, o, 64);
    b += __shfl_xor(b, o, 64);
  }
  int wv = threadIdx.x >> 6;
  if ((threadIdx.x & 63) == 0) { red[wv * 2] = a; red[wv * 2 + 1] = b; }
  __syncthreads();
  a = red[0]; b = red[1];
  #pragma unroll
  for (int i = 1; i < 8; ++i) { a += red[i * 2]; b += red[i * 2 + 1]; }
  __syncthreads();
}

// Wpack per layer: [ncb(64)][kc(16)][nt(4)][ki(4)][lane(64)][j(8)]
// n = ncb*64 + nt*16 + (lane&15); k = kc*128 + ki*32 + (lane>>4)*8 + j
// k<1024 -> Wx[n][k], else Wh[n][k-1024]
__global__ __launch_bounds__(256) void pack_weights(
    const float* __restrict__ Wx, const float* __restrict__ Wh,
    _Float16* __restrict__ Wpack) {
  long idx = (long)blockIdx.x * 256 + threadIdx.x;  // exactly 3*4096*2048 threads
  int l  = (int)(idx / 8388608);
  int r  = (int)(idx % 8388608);
  int ncb = r >> 17;
  int r2 = r & 131071;
  int kc = r2 >> 13;
  int r3 = r2 & 8191;
  int nt = r3 >> 11;
  int r4 = r3 & 2047;
  int ki = r4 >> 9;
  int r5 = r4 & 511;
  int lane = r5 >> 3, j = r5 & 7;
  int n = ncb * 64 + nt * 16 + (lane & 15);
  int k = kc * 128 + ki * 32 + ((lane >> 4) << 3) + j;
  float v = (k < 1024) ? Wx[((size_t)l * 4096 + n) * 1024 + k]
                       : Wh[((size_t)l * 4096 + n) * 1024 + (k - 1024)];
  Wpack[idx] = (_Float16)v;
}

// zero actsA[1..2] + actsB[0..2] (5*65536 halfwords contiguous after actsA[0]),
// zero c_state, pack x[t=0] into actsA[0].
__global__ __launch_bounds__(256) void init_all(
    const float* __restrict__ x, _Float16* __restrict__ actsA,
    float* __restrict__ c_state) {
  int i = blockIdx.x * 256 + threadIdx.x;  // exactly 589824 threads
  if (i < 327680) {
    ((unsigned short*)(actsA + 65536))[i] = 0;
  } else if (i < 327680 + 196608) {
    c_state[i - 327680] = 0.f;
  } else {
    int q = i - (327680 + 196608);
    int b = q >> 10, e = q & 1023;
    actsA[act_pack_idx(b, e)] = (_Float16)x[(size_t)b * 1024 + e];
  }
}

// Persistent-weight cooperative kernel, full-K-per-block.
// Grid: 256 blocks x 512 threads (8 waves). Block b owns output cols
// [b*16, b*16+16) of every layer, FULL K=2048: weight frags = 96 VGPR/lane.
// Wave w owns k-steps ks in {w, w+8, ..., w+56} (ks = k>>5); partial fp32
// accs are reduced across the 8 waves through 32 KB LDS, then written as
// FINAL pre-activations to ifgo (no bias; bias added in phase B).
__global__ __launch_bounds__(512, 2) void lstm_main(
    const float* __restrict__ x, const float* __restrict__ bh,
    const float* __restrict__ ln_g, const float* __restrict__ ln_b,
    const float* __restrict__ lnc_g, const float* __restrict__ lnc_b,
    const _Float16* __restrict__ Wpack,
    _Float16* __restrict__ actsA, _Float16* __restrict__ actsB,
    float* __restrict__ ifgo, float* __restrict__ c_state,
    float* __restrict__ out_all) {
  cg::grid_group grid = cg::this_grid();
  __shared__ float lred[8192];   // 8 waves x 4 mt x 64 lanes x 4 = 32 KB
  __shared__ float red[16];
  const int bid = blockIdx.x, tid = threadIdx.x;
  const int wv = tid >> 6, lane = tid & 63;
  const int ncb = bid >> 2, ntp = bid & 3;

  // ---- preload weights into registers (once): Wreg[l][i] is the B-frag for
  // ks = wv + 8*i, cols [bid*16, +16) ----
  f16x8 Wreg[3][8];
  #pragma unroll
  for (int l = 0; l < 3; ++l)
    #pragma unroll
    for (int i = 0; i < 8; ++i) {
      const int ks = wv + 8 * i;
      const int kc = ks >> 2, ki = ks & 3;
      size_t base = ((((size_t)(l * 64 + ncb) * 16 + kc) * 4 + ntp) * 4 + ki) * 512;
      Wreg[l][i] = *(const f16x8*)(Wpack + base + lane * 8);
    }

  for (int s = 0; s < T_STEPS + NLAYER - 1; ++s) {
    // ---------------- phase A: full-K GEMM, weights in registers ----------------
    #pragma unroll
    for (int l = 0; l < 3; ++l) {
      const int t = s - l;
      if (t >= 0 && t < T_STEPS) {
        const _Float16* aL = actsA + l * 65536;
        const _Float16* bL = actsB + l * 65536;
        f32x4 acc[4];
        #pragma unroll
        for (int mt = 0; mt < 4; ++mt) acc[mt] = (f32x4){0.f, 0.f, 0.f, 0.f};
        #pragma unroll
        for (int mt = 0; mt < 4; ++mt) {
          f16x8 af[8];
          #pragma unroll
          for (int i = 0; i < 8; ++i) {
            const int ks  = wv + 8 * i;
            const _Float16* hb = (i < 4) ? aL : bL;
            const int ks2 = (i < 4) ? ks : (ks - 32);
            const int kc2 = ks2 >> 2, ki2 = ks2 & 3;
            af[i] = *(const f16x8*)(hb + ((kc2 * 4 + mt) * 4 + ki2) * 512 + lane * 8);
          }
          #pragma unroll
          for (int i = 0; i < 8; ++i)
            acc[mt] = __builtin_amdgcn_mfma_f32_16x16x32_f16(af[i], Wreg[l][i], acc[mt], 0, 0, 0);
        }
        __syncthreads();   // lred free (previous layer's readers done)
        #pragma unroll
        for (int mt = 0; mt < 4; ++mt)
          *(f32x4*)(&lred[((wv * 4 + mt) * 64 + lane) * 4]) = acc[mt];
        __syncthreads();
        {
          const int row = tid >> 3;                 // 0..63
          const int mt = row >> 4, q = (row >> 2) & 3, rr = row & 3;
          const int c0 = (tid & 7) * 2;
          float s0 = 0.f, s1 = 0.f;
          #pragma unroll
          for (int w2 = 0; w2 < 8; ++w2) {
            s0 += lred[((w2 * 4 + mt) * 64 + q * 16 + c0) * 4 + rr];
            s1 += lred[((w2 * 4 + mt) * 64 + q * 16 + c0 + 1) * 4 + rr];
          }
          float* op = ifgo + ((size_t)(l * 64 + row)) * 4096 + bid * 16 + c0;
          op[0] = s0; op[1] = s1;
        }
      }
    }
    grid.sync();

    // ---------------- phase B: bias + LN gates + cell + LN(c) + h ----------------
    if (bid < 192) {
      const int l = bid >> 6, row = bid & 63;
      const int t = s - l;
      if (t >= 0 && t < T_STEPS) {
        const float* prow = ifgo + (size_t)(l * 64 + row) * 4096;
        float vv[4][2], actv[4][2];
        #pragma unroll
        for (int g = 0; g < 4; ++g) {
          float a0 = prow[g * 1024 + tid * 2]     + bh[l * 4096 + g * 1024 + tid * 2];
          float a1 = prow[g * 1024 + tid * 2 + 1] + bh[l * 4096 + g * 1024 + tid * 2 + 1];
          vv[g][0] = a0; vv[g][1] = a1;
        }
        #pragma unroll
        for (int g = 0; g < 4; ++g) {
          float s1 = vv[g][0] + vv[g][1];
          float s2 = vv[g][0] * vv[g][0] + vv[g][1] * vv[g][1];
          reduce2_512(s1, s2, red);
          float mu  = s1 * (1.f / 1024.f);
          float var = fmaxf(s2 * (1.f / 1024.f) - mu * mu, 0.f);
          float inv = rsqrtf(var + EPSV);
          #pragma unroll
          for (int j = 0; j < 2; ++j) {
            int e = g * 1024 + tid * 2 + j;
            actv[g][j] = (vv[g][j] - mu) * inv * ln_g[l * 4096 + e] + ln_b[l * 4096 + e];
          }
        }
        float* crow = c_state + (size_t)(l * 64 + row) * 1024 + tid * 2;
        float cold[2] = {crow[0], crow[1]};
        float cn[2];
        float s1 = 0.f, s2 = 0.f;
        #pragma unroll
        for (int j = 0; j < 2; ++j) {
          float ii = sigmoidf_(actv[0][j]);
          float ff = sigmoidf_(actv[1][j]);
          float gg = tanhf(actv[2][j]);
          cn[j] = ff * cold[j] + ii * gg;
          s1 += cn[j]; s2 += cn[j] * cn[j];
        }
        crow[0] = cn[0]; crow[1] = cn[1];
        reduce2_512(s1, s2, red);
        float mu  = s1 * (1.f / 1024.f);
        float var = fmaxf(s2 * (1.f / 1024.f) - mu * mu, 0.f);
        float inv = rsqrtf(var + EPSV);
        float hn[2];
        #pragma unroll
        for (int j = 0; j < 2; ++j) {
          int e = tid * 2 + j;
          float cl = (cn[j] - mu) * inv * lnc_g[l * 1024 + e] + lnc_b[l * 1024 + e];
          hn[j] = sigmoidf_(actv[3][j]) * tanhf(cl);
        }
        _Float16* selfB = actsB + l * 65536;
        #pragma unroll
        for (int j = 0; j < 2; ++j)
          selfB[act_pack_idx(row, tid * 2 + j)] = (_Float16)hn[j];
        if (l < 2) {
          _Float16* nxtA = actsA + (l + 1) * 65536;
          #pragma unroll
          for (int j = 0; j < 2; ++j)
            nxtA[act_pack_idx(row, tid * 2 + j)] = (_Float16)hn[j];
        } else {
          float* op = out_all + ((size_t)t * BATCH + row) * 1024 + tid * 2;
          op[0] = hn[0]; op[1] = hn[1];
        }
        if (t == T_STEPS - 1) {
          float* hsec = out_all + (size_t)T_STEPS * BATCH * 1024
                        + (size_t)(l * BATCH + row) * 1024 + tid * 2;
          float* csec = hsec + (size_t)NLAYER * BATCH * 1024;
          hsec[0] = hn[0]; hsec[1] = hn[1];
          csec[0] = cn[0]; csec[1] = cn[1];
        }
      }
    } else {
      const int row = bid - 192;
      if (s + 1 < T_STEPS) {
        const float* xr = x + ((size_t)(s + 1) * BATCH + row) * 1024 + tid * 2;
        float v0 = xr[0], v1 = xr[1];
        actsA[act_pack_idx(row, tid * 2)]     = (_Float16)v0;
        actsA[act_pack_idx(row, tid * 2 + 1)] = (_Float16)v1;
      }
    }
    grid.sync();
  }
}

extern "C" void kernel_launch(void* const* d_in, const int* in_sizes, int n_in,
                              void* d_out, int out_size, void* d_ws, size_t ws_size,
                              hipStream_t stream) {
  const float* x     = (const float*)d_in[0];
  const float* Wx    = (const float*)d_in[1];
  const float* Wh    = (const float*)d_in[2];
  const float* bh    = (const float*)d_in[3];
  const float* ln_g  = (const float*)d_in[4];
  const float* ln_b  = (const float*)d_in[5];
  const float* lnc_g = (const float*)d_in[6];
  const float* lnc_b = (const float*)d_in[7];

  char* ws = (char*)d_ws;
  _Float16* Wpack = (_Float16*)ws;                               // 50331648 B
  _Float16* actsA = (_Float16*)(ws + 50331648);                  // 393216 B (3 x 65536)
  _Float16* actsB = (_Float16*)(ws + 50724864);                  // 393216 B
  float* ifgo    = (float*)(ws + 51118080);                      // 3145728 B
  float* c_state = (float*)(ws + 54263808);                      // 786432 B
  float* out_all = (float*)d_out;

  pack_weights<<<98304, 256, 0, stream>>>(Wx, Wh, Wpack);
  init_all<<<2304, 256, 0, stream>>>(x, actsA, c_state);

  void* args[] = { (void*)&x, (void*)&bh, (void*)&ln_g, (void*)&ln_b,
                   (void*)&lnc_g, (void*)&lnc_b, (void*)&Wpack, (void*)&actsA,
                   (void*)&actsB, (void*)&ifgo, (void*)&c_state, (void*)&out_all };
  hipLaunchCooperativeKernel((void*)lstm_main, dim3(256), dim3(512), args, 0, stream);
}

// Round 5
// 48557.095 us; speedup vs baseline: 1.0119x; 1.0041x over previous
//
#include <hip/hip_runtime.h>
#include <hip/hip_bf16.h>
#include <hip/hip_cooperative_groups.h>

namespace cg = cooperative_groups;

#define T_STEPS 512
#define BATCH   64
#define HID     1024
#define NLAYER  3
#define EPSV    1e-5f

typedef __attribute__((ext_vector_type(8))) short    short8;
typedef __attribute__((ext_vector_type(8))) _Float16 f16x8;
typedef __attribute__((ext_vector_type(4))) float    f32x4;

// packed activation layout within one [64 rows x 1024 k] fp16 buffer (65536 elems):
// [kc(8)][mt(4)][ki(4)][lane(64)][j(8)]  where row = mt*16 + (lane&15),
// k = kc*128 + ki*32 + (lane>>4)*8 + j
__device__ __forceinline__ int act_pack_idx(int row, int k) {
  int mt = row >> 4, lr = row & 15;
  int kc = k >> 7;
  int ki = (k >> 5) & 3;
  int lh = (k >> 3) & 3;
  int j  = k & 7;
  int lane = lr | (lh << 4);
  return ((((kc * 4 + mt) * 4 + ki) * 64) + lane) * 8 + j;
}

__device__ __forceinline__ float sigmoidf_(float v) {
  return 1.f / (1.f + __expf(-v));
}

// sum-reduce two values across 512 threads (8 waves)
__device__ __forceinline__ void reduce2_512(float& a, float& b, float* red) {
  #pragma unroll
  for (int o = 32; o; o >>= 1) {
    a += __shfl_xor(a, o, 64);
    b += __shfl_xor(b, o, 64);
  }
  int wv = threadIdx.x >> 6;
  if ((threadIdx.x & 63) == 0) { red[wv * 2] = a; red[wv * 2 + 1] = b; }
  __syncthreads();
  a = red[0]; b = red[1];
  #pragma unroll
  for (int i = 1; i < 8; ++i) { a += red[i * 2]; b += red[i * 2 + 1]; }
  __syncthreads();
}

// Wpack per layer: [ncb(64)][kc(16)][nt(4)][ki(4)][lane(64)][j(8)]
// n = ncb*64 + nt*16 + (lane&15); k = kc*128 + ki*32 + (lane>>4)*8 + j
// k<1024 -> Wx[n][k], else Wh[n][k-1024]
__global__ __launch_bounds__(256) void pack_weights(
    const float* __restrict__ Wx, const float* __restrict__ Wh,
    _Float16* __restrict__ Wpack) {
  long idx = (long)blockIdx.x * 256 + threadIdx.x;  // exactly 3*4096*2048 threads
  int l  = (int)(idx / 8388608);
  int r  = (int)(idx % 8388608);
  int ncb = r >> 17;
  int r2 = r & 131071;
  int kc = r2 >> 13;
  int r3 = r2 & 8191;
  int nt = r3 >> 11;
  int r4 = r3 & 2047;
  int ki = r4 >> 9;
  int r5 = r4 & 511;
  int lane = r5 >> 3, j = r5 & 7;
  int n = ncb * 64 + nt * 16 + (lane & 15);
  int k = kc * 128 + ki * 32 + ((lane >> 4) << 3) + j;
  float v = (k < 1024) ? Wx[((size_t)l * 4096 + n) * 1024 + k]
                       : Wh[((size_t)l * 4096 + n) * 1024 + (k - 1024)];
  Wpack[idx] = (_Float16)v;
}

// zero actsA[1..2] + actsB[0..2] (5*65536 halfwords contiguous after actsA[0]),
// zero c_state, pack x[t=0] into actsA[0].
__global__ __launch_bounds__(256) void init_all(
    const float* __restrict__ x, _Float16* __restrict__ actsA,
    float* __restrict__ c_state) {
  int i = blockIdx.x * 256 + threadIdx.x;  // exactly 589824 threads
  if (i < 327680) {
    ((unsigned short*)(actsA + 65536))[i] = 0;
  } else if (i < 327680 + 196608) {
    c_state[i - 327680] = 0.f;
  } else {
    int q = i - (327680 + 196608);
    int b = q >> 10, e = q & 1023;
    actsA[act_pack_idx(b, e)] = (_Float16)x[(size_t)b * 1024 + e];
  }
}

// Persistent-weight cooperative kernel, full-K-per-block.
// Grid: 256 blocks x 512 threads (8 waves). Block b owns output cols
// [b*16, b*16+16) of every layer, FULL K=2048: weight frags = 96 VGPR/lane.
// __launch_bounds__(512, 1): 1 block/CU -> VGPR cap 256 so Wreg STAYS
// register-resident (with (512,2) the 128-VGPR cap forced per-step
// rematerialization = 50 MB/step weight re-fetch, the R3/R4 bottleneck).
__global__ __launch_bounds__(512, 1) void lstm_main(
    const float* __restrict__ x, const float* __restrict__ bh,
    const float* __restrict__ ln_g, const float* __restrict__ ln_b,
    const float* __restrict__ lnc_g, const float* __restrict__ lnc_b,
    const _Float16* __restrict__ Wpack,
    _Float16* __restrict__ actsA, _Float16* __restrict__ actsB,
    float* __restrict__ ifgo, float* __restrict__ c_state,
    float* __restrict__ out_all) {
  cg::grid_group grid = cg::this_grid();
  __shared__ float lred[8192];   // 8 waves x 4 mt x 64 lanes x 4 = 32 KB
  __shared__ float red[16];
  const int bid = blockIdx.x, tid = threadIdx.x;
  const int wv = tid >> 6, lane = tid & 63;
  const int ncb = bid >> 2, ntp = bid & 3;

  // ---- preload weights into registers (once): Wreg[l][i] is the B-frag for
  // ks = wv + 8*i, cols [bid*16, +16) ----
  f16x8 Wreg[3][8];
  #pragma unroll
  for (int l = 0; l < 3; ++l)
    #pragma unroll
    for (int i = 0; i < 8; ++i) {
      const int ks = wv + 8 * i;
      const int kc = ks >> 2, ki = ks & 3;
      size_t base = ((((size_t)(l * 64 + ncb) * 16 + kc) * 4 + ntp) * 4 + ki) * 512;
      Wreg[l][i] = *(const f16x8*)(Wpack + base + lane * 8);
    }

  for (int s = 0; s < T_STEPS + NLAYER - 1; ++s) {
    // ---------------- phase A: full-K GEMM, weights in registers ----------------
    #pragma unroll
    for (int l = 0; l < 3; ++l) {
      const int t = s - l;
      if (t >= 0 && t < T_STEPS) {
        const _Float16* aL = actsA + l * 65536;
        const _Float16* bL = actsB + l * 65536;
        f32x4 acc[4];
        #pragma unroll
        for (int mt = 0; mt < 4; ++mt) acc[mt] = (f32x4){0.f, 0.f, 0.f, 0.f};
        #pragma unroll
        for (int mt = 0; mt < 4; ++mt) {
          f16x8 af[8];
          #pragma unroll
          for (int i = 0; i < 8; ++i) {
            const int ks  = wv + 8 * i;
            const _Float16* hb = (i < 4) ? aL : bL;
            const int ks2 = (i < 4) ? ks : (ks - 32);
            const int kc2 = ks2 >> 2, ki2 = ks2 & 3;
            af[i] = *(const f16x8*)(hb + ((kc2 * 4 + mt) * 4 + ki2) * 512 + lane * 8);
          }
          #pragma unroll
          for (int i = 0; i < 8; ++i)
            acc[mt] = __builtin_amdgcn_mfma_f32_16x16x32_f16(af[i], Wreg[l][i], acc[mt], 0, 0, 0);
        }
        __syncthreads();   // lred free (previous layer's readers done)
        #pragma unroll
        for (int mt = 0; mt < 4; ++mt)
          *(f32x4*)(&lred[((wv * 4 + mt) * 64 + lane) * 4]) = acc[mt];
        __syncthreads();
        {
          const int row = tid >> 3;                 // 0..63
          const int mt = row >> 4, q = (row >> 2) & 3, rr = row & 3;
          const int c0 = (tid & 7) * 2;
          float s0 = 0.f, s1 = 0.f;
          #pragma unroll
          for (int w2 = 0; w2 < 8; ++w2) {
            s0 += lred[((w2 * 4 + mt) * 64 + q * 16 + c0) * 4 + rr];
            s1 += lred[((w2 * 4 + mt) * 64 + q * 16 + c0 + 1) * 4 + rr];
          }
          float* op = ifgo + ((size_t)(l * 64 + row)) * 4096 + bid * 16 + c0;
          op[0] = s0; op[1] = s1;
        }
      }
    }
    grid.sync();

    // ---------------- phase B: bias + LN gates + cell + LN(c) + h ----------------
    if (bid < 192) {
      const int l = bid >> 6, row = bid & 63;
      const int t = s - l;
      if (t >= 0 && t < T_STEPS) {
        const float* prow = ifgo + (size_t)(l * 64 + row) * 4096;
        float vv[4][2], actv[4][2];
        #pragma unroll
        for (int g = 0; g < 4; ++g) {
          float a0 = prow[g * 1024 + tid * 2]     + bh[l * 4096 + g * 1024 + tid * 2];
          float a1 = prow[g * 1024 + tid * 2 + 1] + bh[l * 4096 + g * 1024 + tid * 2 + 1];
          vv[g][0] = a0; vv[g][1] = a1;
        }
        #pragma unroll
        for (int g = 0; g < 4; ++g) {
          float s1 = vv[g][0] + vv[g][1];
          float s2 = vv[g][0] * vv[g][0] + vv[g][1] * vv[g][1];
          reduce2_512(s1, s2, red);
          float mu  = s1 * (1.f / 1024.f);
          float var = fmaxf(s2 * (1.f / 1024.f) - mu * mu, 0.f);
          float inv = rsqrtf(var + EPSV);
          #pragma unroll
          for (int j = 0; j < 2; ++j) {
            int e = g * 1024 + tid * 2 + j;
            actv[g][j] = (vv[g][j] - mu) * inv * ln_g[l * 4096 + e] + ln_b[l * 4096 + e];
          }
        }
        float* crow = c_state + (size_t)(l * 64 + row) * 1024 + tid * 2;
        float cold[2] = {crow[0], crow[1]};
        float cn[2];
        float s1 = 0.f, s2 = 0.f;
        #pragma unroll
        for (int j = 0; j < 2; ++j) {
          float ii = sigmoidf_(actv[0][j]);
          float ff = sigmoidf_(actv[1][j]);
          float gg = tanhf(actv[2][j]);
          cn[j] = ff * cold[j] + ii * gg;
          s1 += cn[j]; s2 += cn[j] * cn[j];
        }
        crow[0] = cn[0]; crow[1] = cn[1];
        reduce2_512(s1, s2, red);
        float mu  = s1 * (1.f / 1024.f);
        float var = fmaxf(s2 * (1.f / 1024.f) - mu * mu, 0.f);
        float inv = rsqrtf(var + EPSV);
        float hn[2];
        #pragma unroll
        for (int j = 0; j < 2; ++j) {
          int e = tid * 2 + j;
          float cl = (cn[j] - mu) * inv * lnc_g[l * 1024 + e] + lnc_b[l * 1024 + e];
          hn[j] = sigmoidf_(actv[3][j]) * tanhf(cl);
        }
        _Float16* selfB = actsB + l * 65536;
        #pragma unroll
        for (int j = 0; j < 2; ++j)
          selfB[act_pack_idx(row, tid * 2 + j)] = (_Float16)hn[j];
        if (l < 2) {
          _Float16* nxtA = actsA + (l + 1) * 65536;
          #pragma unroll
          for (int j = 0; j < 2; ++j)
            nxtA[act_pack_idx(row, tid * 2 + j)] = (_Float16)hn[j];
        } else {
          float* op = out_all + ((size_t)t * BATCH + row) * 1024 + tid * 2;
          op[0] = hn[0]; op[1] = hn[1];
        }
        if (t == T_STEPS - 1) {
          float* hsec = out_all + (size_t)T_STEPS * BATCH * 1024
                        + (size_t)(l * BATCH + row) * 1024 + tid * 2;
          float* csec = hsec + (size_t)NLAYER * BATCH * 1024;
          hsec[0] = hn[0]; hsec[1] = hn[1];
          csec[0] = cn[0]; csec[1] = cn[1];
        }
      }
    } else {
      const int row = bid - 192;
      if (s + 1 < T_STEPS) {
        const float* xr = x + ((size_t)(s + 1) * BATCH + row) * 1024 + tid * 2;
        float v0 = xr[0], v1 = xr[1];
        actsA[act_pack_idx(row, tid * 2)]     = (_Float16)v0;
        actsA[act_pack_idx(row, tid * 2 + 1)] = (_Float16)v1;
      }
    }
    grid.sync();
  }
}

extern "C" void kernel_launch(void* const* d_in, const int* in_sizes, int n_in,
                              void* d_out, int out_size, void* d_ws, size_t ws_size,
                              hipStream_t stream) {
  const float* x     = (const float*)d_in[0];
  const float* Wx    = (const float*)d_in[1];
  const float* Wh    = (const float*)d_in[2];
  const float* bh    = (const float*)d_in[3];
  const float* ln_g  = (const float*)d_in[4];
  const float* ln_b  = (const float*)d_in[5];
  const float* lnc_g = (const float*)d_in[6];
  const float* lnc_b = (const float*)d_in[7];

  char* ws = (char*)d_ws;
  _Float16* Wpack = (_Float16*)ws;                               // 50331648 B
  _Float16* actsA = (_Float16*)(ws + 50331648);                  // 393216 B (3 x 65536)
  _Float16* actsB = (_Float16*)(ws + 50724864);                  // 393216 B
  float* ifgo    = (float*)(ws + 51118080);                      // 3145728 B
  float* c_state = (float*)(ws + 54263808);                      // 786432 B
  float* out_all = (float*)d_out;

  pack_weights<<<98304, 256, 0, stream>>>(Wx, Wh, Wpack);
  init_all<<<2304, 256, 0, stream>>>(x, actsA, c_state);

  void* args[] = { (void*)&x, (void*)&bh, (void*)&ln_g, (void*)&ln_b,
                   (void*)&lnc_g, (void*)&lnc_b, (void*)&Wpack, (void*)&actsA,
                   (void*)&actsB, (void*)&ifgo, (void*)&c_state, (void*)&out_all };
  hipLaunchCooperativeKernel((void*)lstm_main, dim3(256), dim3(512), args, 0, stream);
}